// Round 1
// baseline (8391.384 us; speedup 1.0000x reference)
//
#include <hip/hip_runtime.h>
#include <cstdint>
#include <cstddef>

#define EPI_NONE 0
#define EPI_SILU 1
#define EPI_LOGSIG 2

// ---- bf16 helpers on raw ushort (avoid __hip_bfloat16 ctor issues in LDS arrays) ----
__device__ __forceinline__ float us2f(unsigned short u) {
    unsigned int x = ((unsigned int)u) << 16;
    return __uint_as_float(x);
}
__device__ __forceinline__ unsigned short f2us(float f) {
    unsigned int x = __float_as_uint(f);
    unsigned int r = (x + 0x7fffu + ((x >> 16) & 1u)) >> 16;
    return (unsigned short)r;
}

// =============== GEMM: C[M,N] = act(A[M,K] * B[N,K]^T) ===============
// BM=BN=128, BK=16, 256 threads, 8x8 microtile, fp32.
__global__ __launch_bounds__(256) void gemm_nt(const float* __restrict__ A,
                                               const float* __restrict__ B,
                                               float* __restrict__ C,
                                               int M, int N, int K, int epi)
{
    __shared__ float As[16][132];
    __shared__ float Bs[16][132];
    const int tid = threadIdx.x;
    const int m0 = blockIdx.y * 128;
    const int n0 = blockIdx.x * 128;
    const int lrow = tid >> 1;        // 0..127
    const int lkc  = (tid & 1) << 3;  // 0,8
    const int tm   = (tid >> 4) << 3; // 0..120
    const int tn   = (tid & 15) << 3; // 0..120

    const float* Ap = A + (size_t)(m0 + lrow) * K + lkc;
    const float* Bp = B + (size_t)(n0 + lrow) * K + lkc;

    float acc[8][8];
#pragma unroll
    for (int i = 0; i < 8; ++i)
#pragma unroll
        for (int j = 0; j < 8; ++j) acc[i][j] = 0.f;

    for (int k0 = 0; k0 < K; k0 += 16) {
        float4 a0 = *(const float4*)(Ap + k0);
        float4 a1 = *(const float4*)(Ap + k0 + 4);
        float4 b0 = *(const float4*)(Bp + k0);
        float4 b1 = *(const float4*)(Bp + k0 + 4);
        __syncthreads();
        As[lkc + 0][lrow] = a0.x; As[lkc + 1][lrow] = a0.y;
        As[lkc + 2][lrow] = a0.z; As[lkc + 3][lrow] = a0.w;
        As[lkc + 4][lrow] = a1.x; As[lkc + 5][lrow] = a1.y;
        As[lkc + 6][lrow] = a1.z; As[lkc + 7][lrow] = a1.w;
        Bs[lkc + 0][lrow] = b0.x; Bs[lkc + 1][lrow] = b0.y;
        Bs[lkc + 2][lrow] = b0.z; Bs[lkc + 3][lrow] = b0.w;
        Bs[lkc + 4][lrow] = b1.x; Bs[lkc + 5][lrow] = b1.y;
        Bs[lkc + 6][lrow] = b1.z; Bs[lkc + 7][lrow] = b1.w;
        __syncthreads();
#pragma unroll
        for (int kk = 0; kk < 16; ++kk) {
            float a8[8], b8[8];
            *(float4*)(a8 + 0) = *(const float4*)&As[kk][tm];
            *(float4*)(a8 + 4) = *(const float4*)&As[kk][tm + 4];
            *(float4*)(b8 + 0) = *(const float4*)&Bs[kk][tn];
            *(float4*)(b8 + 4) = *(const float4*)&Bs[kk][tn + 4];
#pragma unroll
            for (int i = 0; i < 8; ++i)
#pragma unroll
                for (int j = 0; j < 8; ++j)
                    acc[i][j] = fmaf(a8[i], b8[j], acc[i][j]);
        }
    }

#pragma unroll
    for (int i = 0; i < 8; ++i) {
        float o8[8];
#pragma unroll
        for (int j = 0; j < 8; ++j) {
            float z = acc[i][j];
            if (epi == EPI_SILU) {
                z = z / (1.f + __expf(-z));
            } else if (epi == EPI_LOGSIG) {
                // reference: f = sigmoid(z); log_f = log_sigmoid(f) = -log1p(exp(-f))
                float s = 1.f / (1.f + __expf(-z));
                z = -log1pf(__expf(-s));
            }
            o8[j] = z;
        }
        float* cp = C + (size_t)(m0 + tm + i) * N + (n0 + tn);
        *(float4*)(cp + 0) = make_float4(o8[0], o8[1], o8[2], o8[3]);
        *(float4*)(cp + 4) = make_float4(o8[4], o8[5], o8[6], o8[7]);
    }
}

// =============== Chunked GLA ===============
// grid = B*H*4 blocks; block handles (b,h) with a 32-wide slice of the value/f dim.
// Sequential over 64 chunks of 64 timesteps. State S[e=128][f=32] in LDS (bf16).
__global__ __launch_bounds__(256) void gla_kernel(const float* __restrict__ qb,
                                                  const float* __restrict__ vb,
                                                  const float* __restrict__ lfb,
                                                  float* __restrict__ ob)
{
    __shared__ unsigned short qd[64][136];   // q_dec[t][e]   (bf16)
    __shared__ unsigned short kd[64][136];   // lf then k_dec[t][e]
    __shared__ unsigned short vc[64][40];    // v[t][f-slice]
    __shared__ unsigned short sc[64][66];    // scores[t][s]
    __shared__ unsigned short Ssh[128][34];  // S[e][f-slice]
    __shared__ float eal[128];               // exp(A_last[e])

    const int tid = threadIdx.x;
    const int bid = blockIdx.x;
    const int fs = bid & 3;
    const int h  = (bid >> 2) & 15;
    const int b  = bid >> 6;
    const int fbase = fs * 32;

    for (int i = tid; i < 128 * 34; i += 256)
        ((unsigned short*)Ssh)[i] = 0;  // bf16 zero

    const size_t bh = (size_t)b * 4096 * 2048 + (size_t)h * 128;

    for (int c = 0; c < 64; ++c) {
        const size_t cbase = bh + (size_t)c * 64 * 2048;
        __syncthreads();
        // ---- Ph1a: cooperative staging of q, log_f, v-slice ----
#pragma unroll
        for (int k = 0; k < 4; ++k) {
            int vi = tid + k * 256;          // 8-elem group 0..1023
            int t = vi >> 4;
            int e8 = (vi & 15) << 3;
            const float* qp = qb + cbase + (size_t)t * 2048 + e8;
            const float* lp = lfb + cbase + (size_t)t * 2048 + e8;
            float4 q0 = *(const float4*)(qp);
            float4 q1 = *(const float4*)(qp + 4);
            float4 l0 = *(const float4*)(lp);
            float4 l1 = *(const float4*)(lp + 4);
            unsigned short* qdst = &qd[t][e8];
            qdst[0] = f2us(q0.x); qdst[1] = f2us(q0.y); qdst[2] = f2us(q0.z); qdst[3] = f2us(q0.w);
            qdst[4] = f2us(q1.x); qdst[5] = f2us(q1.y); qdst[6] = f2us(q1.z); qdst[7] = f2us(q1.w);
            unsigned short* ldst = &kd[t][e8];
            ldst[0] = f2us(l0.x); ldst[1] = f2us(l0.y); ldst[2] = f2us(l0.z); ldst[3] = f2us(l0.w);
            ldst[4] = f2us(l1.x); ldst[5] = f2us(l1.y); ldst[6] = f2us(l1.z); ldst[7] = f2us(l1.w);
        }
        {
            int t = tid >> 2;
            int f8 = (tid & 3) << 3;
            const float* vp = vb + cbase + (size_t)t * 2048 + fbase + f8;
            float4 v0 = *(const float4*)(vp);
            float4 v1 = *(const float4*)(vp + 4);
            unsigned short* vdst = &vc[t][f8];
            vdst[0] = f2us(v0.x); vdst[1] = f2us(v0.y); vdst[2] = f2us(v0.z); vdst[3] = f2us(v0.w);
            vdst[4] = f2us(v1.x); vdst[5] = f2us(v1.y); vdst[6] = f2us(v1.z); vdst[7] = f2us(v1.w);
        }
        __syncthreads();
        // ---- Ph1b: per-channel cumsum + decay factors ----
        if (tid < 128) {
            const int e = tid;
            float a = 0.f;
#pragma unroll 4
            for (int t = 0; t < 64; ++t) {
                float lf = us2f(kd[t][e]);
                a += lf;
                qd[t][e] = f2us(us2f(qd[t][e]) * __expf(a));          // q_dec
                kd[t][e] = f2us((1.f - __expf(lf)) * __expf(-a));      // k_dec
            }
            eal[e] = __expf(a);
        }
        __syncthreads();
        // ---- Ph2: scores[t][s] = sum_e q_dec*k_dec, masked tril ----
        {
            const int t0 = (tid >> 4) << 2;
            const int s0 = (tid & 15) << 2;
            float accs[4][4];
#pragma unroll
            for (int i = 0; i < 4; ++i)
#pragma unroll
                for (int j = 0; j < 4; ++j) accs[i][j] = 0.f;
            for (int e = 0; e < 128; ++e) {
                float q4[4], k4[4];
#pragma unroll
                for (int i = 0; i < 4; ++i) q4[i] = us2f(qd[t0 + i][e]);
#pragma unroll
                for (int j = 0; j < 4; ++j) k4[j] = us2f(kd[s0 + j][e]);
#pragma unroll
                for (int i = 0; i < 4; ++i)
#pragma unroll
                    for (int j = 0; j < 4; ++j)
                        accs[i][j] = fmaf(q4[i], k4[j], accs[i][j]);
            }
#pragma unroll
            for (int i = 0; i < 4; ++i)
#pragma unroll
                for (int j = 0; j < 4; ++j)
                    sc[t0 + i][s0 + j] = f2us((s0 + j <= t0 + i) ? accs[i][j] : 0.f);
        }
        __syncthreads();
        // ---- Ph3: o[t][f] = intra + inter (uses OLD S) ----
        {
            const int t  = tid >> 2;
            const int f0 = (tid & 3) << 3;
            float acc8[8];
#pragma unroll
            for (int j = 0; j < 8; ++j) acc8[j] = 0.f;
            for (int s = 0; s < 64; ++s) {
                float w = us2f(sc[t][s]);
#pragma unroll
                for (int j = 0; j < 8; ++j)
                    acc8[j] = fmaf(w, us2f(vc[s][f0 + j]), acc8[j]);
            }
            for (int e = 0; e < 128; ++e) {
                float qv = us2f(qd[t][e]);
#pragma unroll
                for (int j = 0; j < 8; ++j)
                    acc8[j] = fmaf(qv, us2f(Ssh[e][f0 + j]), acc8[j]);
            }
            float* op = ob + cbase + (size_t)t * 2048 + fbase + f0;
            *(float4*)(op + 0) = make_float4(acc8[0], acc8[1], acc8[2], acc8[3]);
            *(float4*)(op + 4) = make_float4(acc8[4], acc8[5], acc8[6], acc8[7]);
        }
        __syncthreads();
        // ---- Ph4: S = eal * (S + sum_t k_dec[t] ⊗ v[t]) ----
        {
            const int e  = tid >> 1;
            const int f0 = (tid & 1) << 4;
            float accs[16];
#pragma unroll
            for (int j = 0; j < 16; ++j) accs[j] = 0.f;
            for (int t = 0; t < 64; ++t) {
                float kv = us2f(kd[t][e]);
#pragma unroll
                for (int j = 0; j < 16; ++j)
                    accs[j] = fmaf(kv, us2f(vc[t][f0 + j]), accs[j]);
            }
            float ea = eal[e];
#pragma unroll
            for (int j = 0; j < 16; ++j)
                Ssh[e][f0 + j] = f2us(ea * (us2f(Ssh[e][f0 + j]) + accs[j]));
        }
    }
}

// =============== RMSNorm (in-place) ===============
__global__ __launch_bounds__(256) void rmsnorm_kernel(float* __restrict__ o,
                                                      const float* __restrict__ w)
{
    __shared__ float red[4];
    const int row = blockIdx.x;
    const int tid = threadIdx.x;
    float* p = o + (size_t)row * 2048 + tid * 8;
    float4 v0 = *(const float4*)(p);
    float4 v1 = *(const float4*)(p + 4);
    float ss = v0.x * v0.x + v0.y * v0.y + v0.z * v0.z + v0.w * v0.w
             + v1.x * v1.x + v1.y * v1.y + v1.z * v1.z + v1.w * v1.w;
#pragma unroll
    for (int off = 32; off > 0; off >>= 1) ss += __shfl_down(ss, off, 64);
    if ((tid & 63) == 0) red[tid >> 6] = ss;
    __syncthreads();
    float tot = red[0] + red[1] + red[2] + red[3];
    float scale = rsqrtf(tot * (1.f / 2048.f) + 1e-6f);
    const float* wp = w + tid * 8;
    v0.x *= scale * wp[0]; v0.y *= scale * wp[1]; v0.z *= scale * wp[2]; v0.w *= scale * wp[3];
    v1.x *= scale * wp[4]; v1.y *= scale * wp[5]; v1.z *= scale * wp[6]; v1.w *= scale * wp[7];
    *(float4*)(p)     = v0;
    *(float4*)(p + 4) = v1;
}

extern "C" void kernel_launch(void* const* d_in, const int* in_sizes, int n_in,
                              void* d_out, int out_size, void* d_ws, size_t ws_size,
                              hipStream_t stream)
{
    const float* x  = (const float*)d_in[0];
    const float* Wq = (const float*)d_in[1];
    const float* Wk = (const float*)d_in[2];
    const float* Wv = (const float*)d_in[3];
    const float* Wo = (const float*)d_in[4];
    const float* nw = (const float*)d_in[5];
    float* out = (float*)d_out;

    const int M = 16384, N = 2048, K = 2048;
    const size_t S1 = (size_t)M * N;
    float* qbuf = (float*)d_ws;
    float* vbuf = qbuf + S1;
    float* lfbuf = vbuf + S1;
    float* obuf = lfbuf + S1;

    dim3 gg(N / 128, M / 128);
    gemm_nt<<<gg, 256, 0, stream>>>(x, Wq, qbuf, M, N, K, EPI_SILU);
    gemm_nt<<<gg, 256, 0, stream>>>(x, Wk, lfbuf, M, N, K, EPI_LOGSIG);
    gemm_nt<<<gg, 256, 0, stream>>>(x, Wv, vbuf, M, N, K, EPI_NONE);
    gla_kernel<<<256, 256, 0, stream>>>(qbuf, vbuf, lfbuf, obuf);
    rmsnorm_kernel<<<16384, 256, 0, stream>>>(obuf, nw);
    gemm_nt<<<gg, 256, 0, stream>>>(obuf, Wo, out, M, N, K, EPI_NONE);
}

// Round 2
// 2692.295 us; speedup vs baseline: 3.1168x; 3.1168x over previous
//
#include <hip/hip_runtime.h>
#include <cstdint>
#include <cstddef>

#define EPI_NONE 0
#define EPI_SILU 1
#define EPI_LOGSIG 2

typedef __attribute__((ext_vector_type(8))) short bf16x8;
typedef __attribute__((ext_vector_type(4))) float f32x4;

// ---- bf16 helpers on raw ushort ----
__device__ __forceinline__ float us2f(unsigned short u) {
    unsigned int x = ((unsigned int)u) << 16;
    return __uint_as_float(x);
}
__device__ __forceinline__ unsigned short f2us(float f) {
    unsigned int x = __float_as_uint(f);
    unsigned int r = (x + 0x7fffu + ((x >> 16) & 1u)) >> 16;
    return (unsigned short)r;
}

// async global->LDS, 16 bytes per lane; LDS dest = wave-uniform base + lane*16
__device__ __forceinline__ void gl_lds16(const unsigned short* g, unsigned short* l) {
    __builtin_amdgcn_global_load_lds(
        (const __attribute__((address_space(1))) void*)g,
        (__attribute__((address_space(3))) void*)l, 16, 0, 0);
}

// =============== cast fp32 -> bf16, 8 elems/thread ===============
__global__ __launch_bounds__(256) void cast_bf16(const float* __restrict__ in,
                                                 unsigned short* __restrict__ out, int n8)
{
    int i = blockIdx.x * blockDim.x + threadIdx.x;
    if (i >= n8) return;
    const float4* p = (const float4*)(in + (size_t)i * 8);
    float4 a = p[0], b = p[1];
    __align__(16) unsigned short u[8];
    u[0] = f2us(a.x); u[1] = f2us(a.y); u[2] = f2us(a.z); u[3] = f2us(a.w);
    u[4] = f2us(b.x); u[5] = f2us(b.y); u[6] = f2us(b.z); u[7] = f2us(b.w);
    *(uint4*)(out + (size_t)i * 8) = *(const uint4*)u;
}

// =============== bf16 MFMA GEMM: C[M,N] = act(A[M,K] * B[N,K]^T) ===============
// m97 pattern: 128x128 tile, BK=32, 256 thr (4 waves, 2x2 wave grid, 4x4 MFMA
// tiles/wave), global_load_lds width=16, 2-barrier K-loop.
template<int EPI, bool OUT_BF16>
__global__ __launch_bounds__(256) void gemm_bt_mfma(const unsigned short* __restrict__ A,
                                                    const unsigned short* __restrict__ B,
                                                    void* __restrict__ Cv,
                                                    int M, int N, int K)
{
    __shared__ unsigned short As[128 * 32];  // [row][k] row-major, no pad (gl_lds layout)
    __shared__ unsigned short Bs[128 * 32];

    const int tid  = threadIdx.x;
    const int lane = tid & 63;
    const int wv   = tid >> 6;
    const int m0   = blockIdx.y * 128;
    const int n0   = blockIdx.x * 128;
    const int wr   = (wv >> 1) * 64;   // wave row offset in tile
    const int wc   = (wv & 1) * 64;    // wave col offset in tile

    // staging: 8 segments of 16 rows x 32 cols (1024B); wave w does segs w and w+4.
    const int srow = wv * 16 + (lane >> 2);
    const int scol = (lane & 3) * 8;
    const unsigned short* Ag0 = A + (size_t)(m0 + srow) * K + scol;
    const unsigned short* Ag1 = Ag0 + (size_t)64 * K;
    const unsigned short* Bg0 = B + (size_t)(n0 + srow) * K + scol;
    const unsigned short* Bg1 = Bg0 + (size_t)64 * K;
    unsigned short* Al0 = As + wv * 512;
    unsigned short* Al1 = As + (4 + wv) * 512;
    unsigned short* Bl0 = Bs + wv * 512;
    unsigned short* Bl1 = Bs + (4 + wv) * 512;

    f32x4 acc[4][4];
#pragma unroll
    for (int i = 0; i < 4; ++i)
#pragma unroll
        for (int j = 0; j < 4; ++j) acc[i][j] = (f32x4){0.f, 0.f, 0.f, 0.f};

    const int fr = lane & 15;         // fragment row/col within 16x16
    const int fk = (lane >> 4) * 8;   // fragment k offset

    for (int k0 = 0; k0 < K; k0 += 32) {
        __syncthreads();              // WAR: prior tile's ds_reads done
        gl_lds16(Ag0 + k0, Al0);
        gl_lds16(Ag1 + k0, Al1);
        gl_lds16(Bg0 + k0, Bl0);
        gl_lds16(Bg1 + k0, Bl1);
        __syncthreads();              // compiler drains vmcnt before barrier

        bf16x8 af[4], bfr[4];
#pragma unroll
        for (int ti = 0; ti < 4; ++ti)
            af[ti] = *(const bf16x8*)&As[(wr + ti * 16 + fr) * 32 + fk];
#pragma unroll
        for (int tj = 0; tj < 4; ++tj)
            bfr[tj] = *(const bf16x8*)&Bs[(wc + tj * 16 + fr) * 32 + fk];
#pragma unroll
        for (int ti = 0; ti < 4; ++ti)
#pragma unroll
            for (int tj = 0; tj < 4; ++tj)
                acc[ti][tj] = __builtin_amdgcn_mfma_f32_16x16x32_bf16(
                    af[ti], bfr[tj], acc[ti][tj], 0, 0, 0);
    }

    // C/D layout: col = lane&15, row = (lane>>4)*4 + reg  [m89-verified]
    const int crow = (lane >> 4) * 4;
    const int ccol = lane & 15;
#pragma unroll
    for (int ti = 0; ti < 4; ++ti) {
#pragma unroll
        for (int r = 0; r < 4; ++r) {
            const int row = m0 + wr + ti * 16 + crow + r;
#pragma unroll
            for (int tj = 0; tj < 4; ++tj) {
                float z = acc[ti][tj][r];
                if (EPI == EPI_SILU) {
                    z = z / (1.f + __expf(-z));
                } else if (EPI == EPI_LOGSIG) {
                    // f = sigmoid(z); log_f = log_sigmoid(f) = -log1p(exp(-f))
                    float s = 1.f / (1.f + __expf(-z));
                    z = -log1pf(__expf(-s));
                }
                const int col = n0 + wc + tj * 16 + ccol;
                if (OUT_BF16)
                    ((unsigned short*)Cv)[(size_t)row * N + col] = f2us(z);
                else
                    ((float*)Cv)[(size_t)row * N + col] = z;
            }
        }
    }
}

// =============== Chunked GLA (bf16 I/O) ===============
// grid = B*H*4 blocks; block handles (b,h) with a 32-wide slice of the value dim.
// Sequential over 64 chunks of 64 timesteps. State S[e=128][f=32] in LDS (bf16).
__global__ __launch_bounds__(256) void gla_kernel(const unsigned short* __restrict__ qb,
                                                  const unsigned short* __restrict__ vb,
                                                  const unsigned short* __restrict__ lfb,
                                                  unsigned short* __restrict__ ob)
{
    __shared__ unsigned short qd[64][136];   // q_dec[t][e]   (bf16)
    __shared__ unsigned short kd[64][136];   // lf then k_dec[t][e]
    __shared__ unsigned short vc[64][40];    // v[t][f-slice]
    __shared__ unsigned short sc[64][66];    // scores[t][s]
    __shared__ unsigned short Ssh[128][34];  // S[e][f-slice]
    __shared__ float eal[128];               // exp(A_last[e])

    const int tid = threadIdx.x;
    const int bid = blockIdx.x;
    const int fs = bid & 3;
    const int h  = (bid >> 2) & 15;
    const int b  = bid >> 6;
    const int fbase = fs * 32;

    for (int i = tid; i < 128 * 34; i += 256)
        ((unsigned short*)Ssh)[i] = 0;  // bf16 zero

    const size_t bh = (size_t)b * 4096 * 2048 + (size_t)h * 128;

    for (int c = 0; c < 64; ++c) {
        const size_t cbase = bh + (size_t)c * 64 * 2048;
        __syncthreads();
        // ---- Ph1a: stage q, log_f, v-slice (raw bf16 copies) ----
#pragma unroll
        for (int k = 0; k < 4; ++k) {
            int vi = tid + k * 256;          // 8-elem group 0..1023
            int t = vi >> 4;
            int e8 = (vi & 15) << 3;
            *(uint4*)&qd[t][e8] = *(const uint4*)(qb + cbase + (size_t)t * 2048 + e8);
            *(uint4*)&kd[t][e8] = *(const uint4*)(lfb + cbase + (size_t)t * 2048 + e8);
        }
        {
            int t = tid >> 2;
            int f8 = (tid & 3) << 3;
            *(uint4*)&vc[t][f8] = *(const uint4*)(vb + cbase + (size_t)t * 2048 + fbase + f8);
        }
        __syncthreads();
        // ---- Ph1b: per-channel cumsum + decay factors ----
        if (tid < 128) {
            const int e = tid;
            float a = 0.f;
#pragma unroll 4
            for (int t = 0; t < 64; ++t) {
                float lf = us2f(kd[t][e]);
                a += lf;
                qd[t][e] = f2us(us2f(qd[t][e]) * __expf(a));          // q_dec
                kd[t][e] = f2us((1.f - __expf(lf)) * __expf(-a));      // k_dec
            }
            eal[e] = __expf(a);
        }
        __syncthreads();
        // ---- Ph2: scores[t][s] = sum_e q_dec*k_dec, masked tril ----
        {
            const int t0 = (tid >> 4) << 2;
            const int s0 = (tid & 15) << 2;
            float accs[4][4];
#pragma unroll
            for (int i = 0; i < 4; ++i)
#pragma unroll
                for (int j = 0; j < 4; ++j) accs[i][j] = 0.f;
            for (int e = 0; e < 128; ++e) {
                float q4[4], k4[4];
#pragma unroll
                for (int i = 0; i < 4; ++i) q4[i] = us2f(qd[t0 + i][e]);
#pragma unroll
                for (int j = 0; j < 4; ++j) k4[j] = us2f(kd[s0 + j][e]);
#pragma unroll
                for (int i = 0; i < 4; ++i)
#pragma unroll
                    for (int j = 0; j < 4; ++j)
                        accs[i][j] = fmaf(q4[i], k4[j], accs[i][j]);
            }
#pragma unroll
            for (int i = 0; i < 4; ++i)
#pragma unroll
                for (int j = 0; j < 4; ++j)
                    sc[t0 + i][s0 + j] = f2us((s0 + j <= t0 + i) ? accs[i][j] : 0.f);
        }
        __syncthreads();
        // ---- Ph3: o[t][f] = intra + inter (uses OLD S) ----
        {
            const int t  = tid >> 2;
            const int f0 = (tid & 3) << 3;
            float acc8[8];
#pragma unroll
            for (int j = 0; j < 8; ++j) acc8[j] = 0.f;
            for (int s = 0; s < 64; ++s) {
                float w = us2f(sc[t][s]);
#pragma unroll
                for (int j = 0; j < 8; ++j)
                    acc8[j] = fmaf(w, us2f(vc[s][f0 + j]), acc8[j]);
            }
            for (int e = 0; e < 128; ++e) {
                float qv = us2f(qd[t][e]);
#pragma unroll
                for (int j = 0; j < 8; ++j)
                    acc8[j] = fmaf(qv, us2f(Ssh[e][f0 + j]), acc8[j]);
            }
            __align__(16) unsigned short ou[8];
#pragma unroll
            for (int j = 0; j < 8; ++j) ou[j] = f2us(acc8[j]);
            *(uint4*)(ob + cbase + (size_t)t * 2048 + fbase + f0) = *(const uint4*)ou;
        }
        __syncthreads();
        // ---- Ph4: S = eal * (S + sum_t k_dec[t] (x) v[t]) ----
        {
            const int e  = tid >> 1;
            const int f0 = (tid & 1) << 4;
            float accs[16];
#pragma unroll
            for (int j = 0; j < 16; ++j) accs[j] = 0.f;
            for (int t = 0; t < 64; ++t) {
                float kv = us2f(kd[t][e]);
#pragma unroll
                for (int j = 0; j < 16; ++j)
                    accs[j] = fmaf(kv, us2f(vc[t][f0 + j]), accs[j]);
            }
            float ea = eal[e];
#pragma unroll
            for (int j = 0; j < 16; ++j)
                Ssh[e][f0 + j] = f2us(ea * (us2f(Ssh[e][f0 + j]) + accs[j]));
        }
    }
}

// =============== RMSNorm (in-place, bf16) ===============
__global__ __launch_bounds__(256) void rmsnorm_kernel(unsigned short* __restrict__ o,
                                                      const float* __restrict__ w)
{
    __shared__ float red[4];
    const int row = blockIdx.x;
    const int tid = threadIdx.x;
    unsigned short* p = o + (size_t)row * 2048 + tid * 8;
    __align__(16) unsigned short u[8];
    *(uint4*)u = *(const uint4*)p;
    float f[8];
    float ss = 0.f;
#pragma unroll
    for (int j = 0; j < 8; ++j) { f[j] = us2f(u[j]); ss = fmaf(f[j], f[j], ss); }
#pragma unroll
    for (int off = 32; off > 0; off >>= 1) ss += __shfl_down(ss, off, 64);
    if ((tid & 63) == 0) red[tid >> 6] = ss;
    __syncthreads();
    float tot = red[0] + red[1] + red[2] + red[3];
    float scale = rsqrtf(tot * (1.f / 2048.f) + 1e-6f);
    const float* wp = w + tid * 8;
#pragma unroll
    for (int j = 0; j < 8; ++j) u[j] = f2us(f[j] * scale * wp[j]);
    *(uint4*)p = *(const uint4*)u;
}

extern "C" void kernel_launch(void* const* d_in, const int* in_sizes, int n_in,
                              void* d_out, int out_size, void* d_ws, size_t ws_size,
                              hipStream_t stream)
{
    const float* x  = (const float*)d_in[0];
    const float* Wq = (const float*)d_in[1];
    const float* Wk = (const float*)d_in[2];
    const float* Wv = (const float*)d_in[3];
    const float* Wo = (const float*)d_in[4];
    const float* nw = (const float*)d_in[5];
    float* out = (float*)d_out;

    const int M = 16384, N = 2048, K = 2048;
    const size_t S1 = (size_t)M * N;       // 33.5M
    const size_t SW = (size_t)N * K;       // 4.19M

    unsigned short* xb  = (unsigned short*)d_ws;
    unsigned short* Wqb = xb + S1;
    unsigned short* Wkb = Wqb + SW;
    unsigned short* Wvb = Wkb + SW;
    unsigned short* Wob = Wvb + SW;
    unsigned short* qb  = Wob + SW;
    unsigned short* vbf = qb + S1;
    unsigned short* lfb = vbf + S1;
    unsigned short* obf = lfb + S1;

    cast_bf16<<<(int)(S1 / 8 / 256), 256, 0, stream>>>(x, xb, (int)(S1 / 8));
    cast_bf16<<<(int)(SW / 8 / 256), 256, 0, stream>>>(Wq, Wqb, (int)(SW / 8));
    cast_bf16<<<(int)(SW / 8 / 256), 256, 0, stream>>>(Wk, Wkb, (int)(SW / 8));
    cast_bf16<<<(int)(SW / 8 / 256), 256, 0, stream>>>(Wv, Wvb, (int)(SW / 8));
    cast_bf16<<<(int)(SW / 8 / 256), 256, 0, stream>>>(Wo, Wob, (int)(SW / 8));

    dim3 gg(N / 128, M / 128);
    gemm_bt_mfma<EPI_SILU,  true><<<gg, 256, 0, stream>>>(xb, Wqb, qb,  M, N, K);
    gemm_bt_mfma<EPI_LOGSIG,true><<<gg, 256, 0, stream>>>(xb, Wkb, lfb, M, N, K);
    gemm_bt_mfma<EPI_NONE,  true><<<gg, 256, 0, stream>>>(xb, Wvb, vbf, M, N, K);

    gla_kernel<<<256, 256, 0, stream>>>(qb, vbf, lfb, obf);
    rmsnorm_kernel<<<16384, 256, 0, stream>>>(obf, nw);

    gemm_bt_mfma<EPI_NONE, false><<<gg, 256, 0, stream>>>(obf, Wob, out, M, N, K);
}

// Round 3
// 1356.384 us; speedup vs baseline: 6.1866x; 1.9849x over previous
//
#include <hip/hip_runtime.h>
#include <cstdint>
#include <cstddef>

#define EPI_NONE 0
#define EPI_SILU 1
#define EPI_LOGSIG 2

typedef __attribute__((ext_vector_type(8))) short bf16x8;
typedef __attribute__((ext_vector_type(4))) float f32x4;

// ---- bf16 helpers on raw ushort ----
__device__ __forceinline__ float us2f(unsigned short u) {
    unsigned int x = ((unsigned int)u) << 16;
    return __uint_as_float(x);
}
__device__ __forceinline__ unsigned short f2us(float f) {
    unsigned int x = __float_as_uint(f);
    unsigned int r = (x + 0x7fffu + ((x >> 16) & 1u)) >> 16;
    return (unsigned short)r;
}

// async global->LDS, 16 bytes per lane
__device__ __forceinline__ void gl_lds16(const unsigned short* g, unsigned short* l) {
    __builtin_amdgcn_global_load_lds(
        (const __attribute__((address_space(1))) void*)g,
        (__attribute__((address_space(3))) void*)l, 16, 0, 0);
}

// =============== cast fp32 -> bf16, 8 elems/thread ===============
__global__ __launch_bounds__(256) void cast_bf16(const float* __restrict__ in,
                                                 unsigned short* __restrict__ out, int n8)
{
    int i = blockIdx.x * blockDim.x + threadIdx.x;
    if (i >= n8) return;
    const float4* p = (const float4*)(in + (size_t)i * 8);
    float4 a = p[0], b = p[1];
    __align__(16) unsigned short u[8];
    u[0] = f2us(a.x); u[1] = f2us(a.y); u[2] = f2us(a.z); u[3] = f2us(a.w);
    u[4] = f2us(b.x); u[5] = f2us(b.y); u[6] = f2us(b.z); u[7] = f2us(b.w);
    *(uint4*)(out + (size_t)i * 8) = *(const uint4*)u;
}

// =============== bf16 MFMA GEMM: C[M,N] = act(A[M,K] * B[N,K]^T) ===============
template<int EPI, bool OUT_BF16>
__global__ __launch_bounds__(256) void gemm_bt_mfma(const unsigned short* __restrict__ A,
                                                    const unsigned short* __restrict__ B,
                                                    void* __restrict__ Cv,
                                                    int M, int N, int K)
{
    __shared__ unsigned short As[128 * 32];
    __shared__ unsigned short Bs[128 * 32];

    const int tid  = threadIdx.x;
    const int lane = tid & 63;
    const int wv   = tid >> 6;
    const int m0   = blockIdx.y * 128;
    const int n0   = blockIdx.x * 128;
    const int wr   = (wv >> 1) * 64;
    const int wc   = (wv & 1) * 64;

    const int srow = wv * 16 + (lane >> 2);
    const int scol = (lane & 3) * 8;
    const unsigned short* Ag0 = A + (size_t)(m0 + srow) * K + scol;
    const unsigned short* Ag1 = Ag0 + (size_t)64 * K;
    const unsigned short* Bg0 = B + (size_t)(n0 + srow) * K + scol;
    const unsigned short* Bg1 = Bg0 + (size_t)64 * K;
    unsigned short* Al0 = As + wv * 512;
    unsigned short* Al1 = As + (4 + wv) * 512;
    unsigned short* Bl0 = Bs + wv * 512;
    unsigned short* Bl1 = Bs + (4 + wv) * 512;

    f32x4 acc[4][4];
#pragma unroll
    for (int i = 0; i < 4; ++i)
#pragma unroll
        for (int j = 0; j < 4; ++j) acc[i][j] = (f32x4){0.f, 0.f, 0.f, 0.f};

    const int fr = lane & 15;
    const int fk = (lane >> 4) * 8;

    for (int k0 = 0; k0 < K; k0 += 32) {
        __syncthreads();
        gl_lds16(Ag0 + k0, Al0);
        gl_lds16(Ag1 + k0, Al1);
        gl_lds16(Bg0 + k0, Bl0);
        gl_lds16(Bg1 + k0, Bl1);
        __syncthreads();

        bf16x8 af[4], bfr[4];
#pragma unroll
        for (int ti = 0; ti < 4; ++ti)
            af[ti] = *(const bf16x8*)&As[(wr + ti * 16 + fr) * 32 + fk];
#pragma unroll
        for (int tj = 0; tj < 4; ++tj)
            bfr[tj] = *(const bf16x8*)&Bs[(wc + tj * 16 + fr) * 32 + fk];
#pragma unroll
        for (int ti = 0; ti < 4; ++ti)
#pragma unroll
            for (int tj = 0; tj < 4; ++tj)
                acc[ti][tj] = __builtin_amdgcn_mfma_f32_16x16x32_bf16(
                    af[ti], bfr[tj], acc[ti][tj], 0, 0, 0);
    }

    const int crow = (lane >> 4) * 4;
    const int ccol = lane & 15;
#pragma unroll
    for (int ti = 0; ti < 4; ++ti) {
#pragma unroll
        for (int r = 0; r < 4; ++r) {
            const int row = m0 + wr + ti * 16 + crow + r;
#pragma unroll
            for (int tj = 0; tj < 4; ++tj) {
                float z = acc[ti][tj][r];
                if (EPI == EPI_SILU) {
                    z = z / (1.f + __expf(-z));
                } else if (EPI == EPI_LOGSIG) {
                    float s = 1.f / (1.f + __expf(-z));
                    z = -log1pf(__expf(-s));
                }
                const int col = n0 + wc + tj * 16 + ccol;
                if (OUT_BF16)
                    ((unsigned short*)Cv)[(size_t)row * N + col] = f2us(z);
                else
                    ((float*)Cv)[(size_t)row * N + col] = z;
            }
        }
    }
}

// =============== GLA pass A1: decays + scores + intra (per chunk,bh) ===============
// grid 4096 = (c<<6)|bh. Writes qdec->qb (inplace), kdec->lfb (inplace), d->dbuf,
// o_intra in MFMA-frag-linear layout -> obf.
__global__ __launch_bounds__(256) void gla_a1(unsigned short* __restrict__ qb,
                                              unsigned short* __restrict__ lfb,
                                              const unsigned short* __restrict__ vb,
                                              unsigned short* __restrict__ obf,
                                              float* __restrict__ dbuf)
{
    __shared__ unsigned short q_sh[64][136];
    __shared__ unsigned short kd_sh[64][136];
    __shared__ unsigned short vT[128][72];   // v^T [f][t]
    __shared__ unsigned short sc[64][72];    // scores [t][s]

    const int tid = threadIdx.x;
    const int bid = blockIdx.x;
    const int c = bid >> 6, bh = bid & 63;
    const int b = bh >> 4, h = bh & 15;
    const size_t tok0 = ((size_t)b * 4096 + (size_t)c * 64) * 2048 + (size_t)h * 128;

    // stage q, lf (coalesced uint4)
#pragma unroll
    for (int k = 0; k < 4; ++k) {
        int vi = tid + k * 256;
        int t = vi >> 4, e8 = (vi & 15) << 3;
        *(uint4*)&q_sh[t][e8]  = *(const uint4*)(qb  + tok0 + (size_t)t * 2048 + e8);
        *(uint4*)&kd_sh[t][e8] = *(const uint4*)(lfb + tok0 + (size_t)t * 2048 + e8);
    }
    // vT via 8x8 register transpose (threads 0..127; 128 8x8 blocks)
    if (tid < 128) {
        int t8 = tid >> 4, f8 = tid & 15;
        __align__(16) unsigned short a[8][8];
#pragma unroll
        for (int r = 0; r < 8; ++r)
            *(uint4*)a[r] = *(const uint4*)(vb + tok0 + (size_t)(t8 * 8 + r) * 2048 + f8 * 8);
#pragma unroll
        for (int j = 0; j < 8; ++j) {
            __align__(16) unsigned short w8[8];
#pragma unroll
            for (int r = 0; r < 8; ++r) w8[r] = a[r][j];
            *(uint4*)&vT[f8 * 8 + j][t8 * 8] = *(const uint4*)w8;
        }
    }
    __syncthreads();
    // cumsum + decay factors (one channel per thread, 128 channels)
    if (tid < 128) {
        const int e = tid;
        float a = 0.f;
        for (int t = 0; t < 64; ++t) {
            float lf = us2f(kd_sh[t][e]);
            a += lf;
            q_sh[t][e]  = f2us(us2f(q_sh[t][e]) * __expf(a));       // q_dec
            kd_sh[t][e] = f2us((1.f - __expf(lf)) * __expf(-a));    // k_dec
        }
        dbuf[(size_t)bid * 128 + e] = __expf(a);
    }
    __syncthreads();
    // write qdec,kdec back to HBM (pass C / A2 inputs)
#pragma unroll
    for (int k = 0; k < 4; ++k) {
        int vi = tid + k * 256;
        int t = vi >> 4, e8 = (vi & 15) << 3;
        *(uint4*)(qb  + tok0 + (size_t)t * 2048 + e8) = *(const uint4*)&q_sh[t][e8];
        *(uint4*)(lfb + tok0 + (size_t)t * 2048 + e8) = *(const uint4*)&kd_sh[t][e8];
    }

    const int lane = tid & 63, w = tid >> 6;
    const int fr = lane & 15, fq = lane >> 4;

    // scores = qdec @ kdec^T  (wave w -> rows 16w..16w+15, 4 s-tiles)
    f32x4 sacc[4];
#pragma unroll
    for (int j = 0; j < 4; ++j) sacc[j] = (f32x4){0.f, 0.f, 0.f, 0.f};
#pragma unroll
    for (int ke = 0; ke < 4; ++ke) {
        bf16x8 af = *(const bf16x8*)&q_sh[16 * w + fr][ke * 32 + fq * 8];
#pragma unroll
        for (int tj = 0; tj < 4; ++tj) {
            bf16x8 bfv = *(const bf16x8*)&kd_sh[16 * tj + fr][ke * 32 + fq * 8];
            sacc[tj] = __builtin_amdgcn_mfma_f32_16x16x32_bf16(af, bfv, sacc[tj], 0, 0, 0);
        }
    }
    // mask (keep s<=t) + LDS round-trip
#pragma unroll
    for (int tj = 0; tj < 4; ++tj)
#pragma unroll
        for (int r = 0; r < 4; ++r) {
            int trow = 16 * w + fq * 4 + r;
            int scol = 16 * tj + fr;
            sc[trow][scol] = f2us(scol <= trow ? sacc[tj][r] : 0.f);
        }
    __syncthreads();
    // intra = sc @ v  (B-operand = vT)
    f32x4 oacc[8];
#pragma unroll
    for (int j = 0; j < 8; ++j) oacc[j] = (f32x4){0.f, 0.f, 0.f, 0.f};
#pragma unroll
    for (int ks = 0; ks < 2; ++ks) {
        bf16x8 af = *(const bf16x8*)&sc[16 * w + fr][ks * 32 + fq * 8];
#pragma unroll
        for (int tf = 0; tf < 8; ++tf) {
            bf16x8 bfv = *(const bf16x8*)&vT[16 * tf + fr][ks * 32 + fq * 8];
            oacc[tf] = __builtin_amdgcn_mfma_f32_16x16x32_bf16(af, bfv, oacc[tf], 0, 0, 0);
        }
    }
    // store frags (frag-linear: [bid][w][tf][lane][4])
#pragma unroll
    for (int tf = 0; tf < 8; ++tf) {
        __align__(8) unsigned short o4[4];
#pragma unroll
        for (int r = 0; r < 4; ++r) o4[r] = f2us(oacc[tf][r]);
        *(uint2*)(obf + (((size_t)bid * 4 + w) * 8 + tf) * 256 + lane * 4) = *(const uint2*)o4;
    }
}

// =============== GLA pass A2: U^T[f][e] = d[e] * sum_t kdec[t][e] v[t][f] ===============
__global__ __launch_bounds__(256) void gla_a2(const unsigned short* __restrict__ lfb, // kdec
                                              const unsigned short* __restrict__ vb,
                                              const float* __restrict__ dbuf,
                                              unsigned short* __restrict__ UT)
{
    __shared__ unsigned short vT[128][72];
    __shared__ unsigned short kdT[128][72];
    __shared__ float d_sh[128];

    const int tid = threadIdx.x;
    const int bid = blockIdx.x;
    const int c = bid >> 6, bh = bid & 63;
    const int b = bh >> 4, h = bh & 15;
    const size_t tok0 = ((size_t)b * 4096 + (size_t)c * 64) * 2048 + (size_t)h * 128;

    if (tid < 128) {
        int t8 = tid >> 4, f8 = tid & 15;
        __align__(16) unsigned short a[8][8];
#pragma unroll
        for (int r = 0; r < 8; ++r)
            *(uint4*)a[r] = *(const uint4*)(vb + tok0 + (size_t)(t8 * 8 + r) * 2048 + f8 * 8);
#pragma unroll
        for (int j = 0; j < 8; ++j) {
            __align__(16) unsigned short w8[8];
#pragma unroll
            for (int r = 0; r < 8; ++r) w8[r] = a[r][j];
            *(uint4*)&vT[f8 * 8 + j][t8 * 8] = *(const uint4*)w8;
        }
        d_sh[tid] = dbuf[(size_t)bid * 128 + tid];
    } else {
        int i = tid - 128;
        int t8 = i >> 4, e8b = i & 15;
        __align__(16) unsigned short a[8][8];
#pragma unroll
        for (int r = 0; r < 8; ++r)
            *(uint4*)a[r] = *(const uint4*)(lfb + tok0 + (size_t)(t8 * 8 + r) * 2048 + e8b * 8);
#pragma unroll
        for (int j = 0; j < 8; ++j) {
            __align__(16) unsigned short w8[8];
#pragma unroll
            for (int r = 0; r < 8; ++r) w8[r] = a[r][j];
            *(uint4*)&kdT[e8b * 8 + j][t8 * 8] = *(const uint4*)w8;
        }
    }
    __syncthreads();

    const int lane = tid & 63, w = tid >> 6;
    const int fr = lane & 15, fq = lane >> 4;

    // A = vT (m=f), B = kdT (n=e), K=t=64. wave w -> f-tiles 2w,2w+1.
    f32x4 acc[2][8];
#pragma unroll
    for (int mi = 0; mi < 2; ++mi)
#pragma unroll
        for (int te = 0; te < 8; ++te) acc[mi][te] = (f32x4){0.f, 0.f, 0.f, 0.f};
#pragma unroll
    for (int kt = 0; kt < 2; ++kt) {
        bf16x8 af0 = *(const bf16x8*)&vT[16 * (2 * w + 0) + fr][kt * 32 + fq * 8];
        bf16x8 af1 = *(const bf16x8*)&vT[16 * (2 * w + 1) + fr][kt * 32 + fq * 8];
#pragma unroll
        for (int te = 0; te < 8; ++te) {
            bf16x8 bfv = *(const bf16x8*)&kdT[16 * te + fr][kt * 32 + fq * 8];
            acc[0][te] = __builtin_amdgcn_mfma_f32_16x16x32_bf16(af0, bfv, acc[0][te], 0, 0, 0);
            acc[1][te] = __builtin_amdgcn_mfma_f32_16x16x32_bf16(af1, bfv, acc[1][te], 0, 0, 0);
        }
    }
    unsigned short* up = UT + (size_t)bid * 16384;
#pragma unroll
    for (int mi = 0; mi < 2; ++mi)
#pragma unroll
        for (int te = 0; te < 8; ++te) {
            int e = 16 * te + fr;
            float dv = d_sh[e];
#pragma unroll
            for (int r = 0; r < 4; ++r) {
                int f = 32 * w + 16 * mi + fq * 4 + r;
                up[f * 128 + e] = f2us(acc[mi][te][r] * dv);
            }
        }
}

// =============== GLA pass B: in-place scan UT[c] -> S-before-chunk-c ===============
// grid 512 = (bh<<3)|fslice; elementwise recurrence S = d[e]*S + U.
__global__ __launch_bounds__(256) void gla_scan(unsigned short* __restrict__ UT,
                                                const float* __restrict__ dbuf)
{
    const int tid = threadIdx.x;
    const int bh = blockIdx.x >> 3, fs = blockIdx.x & 7;
    const int f = fs * 16 + (tid >> 4);
    const int e8 = (tid & 15) << 3;
    float S[8];
#pragma unroll
    for (int j = 0; j < 8; ++j) S[j] = 0.f;
    for (int c = 0; c < 64; ++c) {
        const size_t cb = (size_t)(c * 64 + bh);
        const size_t loc = cb * 16384 + (size_t)f * 128 + e8;
        uint4 uu = *(const uint4*)(UT + loc);
        float4 d0 = *(const float4*)(dbuf + cb * 128 + e8);
        float4 d1 = *(const float4*)(dbuf + cb * 128 + e8 + 4);
        __align__(16) unsigned short us8[8];
        *(uint4*)us8 = uu;
        __align__(16) unsigned short so[8];
#pragma unroll
        for (int j = 0; j < 8; ++j) so[j] = f2us(S[j]);
        *(uint4*)(UT + loc) = *(const uint4*)so;
        float dd[8] = {d0.x, d0.y, d0.z, d0.w, d1.x, d1.y, d1.z, d1.w};
#pragma unroll
        for (int j = 0; j < 8; ++j) S[j] = fmaf(dd[j], S[j], us2f(us8[j]));
    }
}

// =============== GLA pass C: o = intra + qdec @ S^T; write o over qb ===============
__global__ __launch_bounds__(256) void gla_c(unsigned short* __restrict__ qb,
                                             const unsigned short* __restrict__ UT, // = S^T[f][e]
                                             const unsigned short* __restrict__ obf)
{
    __shared__ unsigned short q_sh[64][136];
    __shared__ unsigned short ST_sh[128][136];

    const int tid = threadIdx.x;
    const int bid = blockIdx.x;
    const int c = bid >> 6, bh = bid & 63;
    const int b = bh >> 4, h = bh & 15;
    const size_t tok0 = ((size_t)b * 4096 + (size_t)c * 64) * 2048 + (size_t)h * 128;

#pragma unroll
    for (int k = 0; k < 4; ++k) {
        int vi = tid + k * 256;
        int t = vi >> 4, e8 = (vi & 15) << 3;
        *(uint4*)&q_sh[t][e8] = *(const uint4*)(qb + tok0 + (size_t)t * 2048 + e8);
    }
    const unsigned short* stp = UT + (size_t)bid * 16384;
#pragma unroll
    for (int k = 0; k < 8; ++k) {
        int vi = tid + k * 256;
        int f = vi >> 4, e8 = (vi & 15) << 3;
        *(uint4*)&ST_sh[f][e8] = *(const uint4*)(stp + (size_t)f * 128 + e8);
    }
    const int lane = tid & 63, w = tid >> 6;
    const int fr = lane & 15, fq = lane >> 4;

    // init acc from intra frags
    f32x4 acc[8];
#pragma unroll
    for (int tf = 0; tf < 8; ++tf) {
        uint2 iv = *(const uint2*)(obf + (((size_t)bid * 4 + w) * 8 + tf) * 256 + lane * 4);
        __align__(8) unsigned short s4[4];
        *(uint2*)s4 = iv;
        acc[tf] = (f32x4){us2f(s4[0]), us2f(s4[1]), us2f(s4[2]), us2f(s4[3])};
    }
    __syncthreads();
    // inter: A = qdec[t][e], B = ST[f][e]
#pragma unroll
    for (int ke = 0; ke < 4; ++ke) {
        bf16x8 af = *(const bf16x8*)&q_sh[16 * w + fr][ke * 32 + fq * 8];
#pragma unroll
        for (int tf = 0; tf < 8; ++tf) {
            bf16x8 bfv = *(const bf16x8*)&ST_sh[16 * tf + fr][ke * 32 + fq * 8];
            acc[tf] = __builtin_amdgcn_mfma_f32_16x16x32_bf16(af, bfv, acc[tf], 0, 0, 0);
        }
    }
    // store o (natural layout) over qb
#pragma unroll
    for (int tf = 0; tf < 8; ++tf)
#pragma unroll
        for (int r = 0; r < 4; ++r) {
            int t = 16 * w + fq * 4 + r;
            qb[tok0 + (size_t)t * 2048 + 16 * tf + fr] = f2us(acc[tf][r]);
        }
}

// =============== RMSNorm (in-place, bf16) ===============
__global__ __launch_bounds__(256) void rmsnorm_kernel(unsigned short* __restrict__ o,
                                                      const float* __restrict__ w)
{
    __shared__ float red[4];
    const int row = blockIdx.x;
    const int tid = threadIdx.x;
    unsigned short* p = o + (size_t)row * 2048 + tid * 8;
    __align__(16) unsigned short u[8];
    *(uint4*)u = *(const uint4*)p;
    float f[8];
    float ss = 0.f;
#pragma unroll
    for (int j = 0; j < 8; ++j) { f[j] = us2f(u[j]); ss = fmaf(f[j], f[j], ss); }
#pragma unroll
    for (int off = 32; off > 0; off >>= 1) ss += __shfl_down(ss, off, 64);
    if ((tid & 63) == 0) red[tid >> 6] = ss;
    __syncthreads();
    float tot = red[0] + red[1] + red[2] + red[3];
    float scale = rsqrtf(tot * (1.f / 2048.f) + 1e-6f);
    const float* wp = w + tid * 8;
#pragma unroll
    for (int j = 0; j < 8; ++j) u[j] = f2us(f[j] * scale * wp[j]);
    *(uint4*)p = *(const uint4*)u;
}

extern "C" void kernel_launch(void* const* d_in, const int* in_sizes, int n_in,
                              void* d_out, int out_size, void* d_ws, size_t ws_size,
                              hipStream_t stream)
{
    const float* x  = (const float*)d_in[0];
    const float* Wq = (const float*)d_in[1];
    const float* Wk = (const float*)d_in[2];
    const float* Wv = (const float*)d_in[3];
    const float* Wo = (const float*)d_in[4];
    const float* nw = (const float*)d_in[5];
    float* out = (float*)d_out;

    const int M = 16384, N = 2048, K = 2048;
    const size_t S1 = (size_t)M * N;       // 33.55M elems
    const size_t SW = (size_t)N * K;       // 4.19M
    const size_t UTsz = (size_t)4096 * 16384;

    unsigned short* xb  = (unsigned short*)d_ws;
    unsigned short* Wqb = xb + S1;
    unsigned short* Wkb = Wqb + SW;
    unsigned short* Wvb = Wkb + SW;
    unsigned short* Wob = Wvb + SW;
    unsigned short* qb  = Wob + SW;   // q -> qdec -> o
    unsigned short* vbf = qb + S1;
    unsigned short* lfb = vbf + S1;   // log_f -> kdec
    unsigned short* obf = lfb + S1;   // intra frags
    unsigned short* UT  = obf + S1;   // U^T then S^T (in-place scan)
    float* dbuf = (float*)(UT + UTsz);

    cast_bf16<<<(int)(S1 / 8 / 256), 256, 0, stream>>>(x, xb, (int)(S1 / 8));
    cast_bf16<<<(int)(SW / 8 / 256), 256, 0, stream>>>(Wq, Wqb, (int)(SW / 8));
    cast_bf16<<<(int)(SW / 8 / 256), 256, 0, stream>>>(Wk, Wkb, (int)(SW / 8));
    cast_bf16<<<(int)(SW / 8 / 256), 256, 0, stream>>>(Wv, Wvb, (int)(SW / 8));
    cast_bf16<<<(int)(SW / 8 / 256), 256, 0, stream>>>(Wo, Wob, (int)(SW / 8));

    dim3 gg(N / 128, M / 128);
    gemm_bt_mfma<EPI_SILU,  true><<<gg, 256, 0, stream>>>(xb, Wqb, qb,  M, N, K);
    gemm_bt_mfma<EPI_LOGSIG,true><<<gg, 256, 0, stream>>>(xb, Wkb, lfb, M, N, K);
    gemm_bt_mfma<EPI_NONE,  true><<<gg, 256, 0, stream>>>(xb, Wvb, vbf, M, N, K);

    gla_a1<<<4096, 256, 0, stream>>>(qb, lfb, vbf, obf, dbuf);
    gla_a2<<<4096, 256, 0, stream>>>(lfb, vbf, dbuf, UT);
    gla_scan<<<512, 256, 0, stream>>>(UT, dbuf);
    gla_c<<<4096, 256, 0, stream>>>(qb, UT, obf);

    rmsnorm_kernel<<<16384, 256, 0, stream>>>(qb, nw);
    gemm_bt_mfma<EPI_NONE, false><<<gg, 256, 0, stream>>>(qb, Wob, out, M, N, K);
}

// Round 4
// 1348.527 us; speedup vs baseline: 6.2226x; 1.0058x over previous
//
#include <hip/hip_runtime.h>
#include <cstdint>
#include <cstddef>

#define EPI_NONE 0
#define EPI_SILU 1
#define EPI_LOGSIG 2

typedef __attribute__((ext_vector_type(8))) short bf16x8;
typedef __attribute__((ext_vector_type(4))) float f32x4;

// ---- bf16 helpers on raw ushort ----
__device__ __forceinline__ float us2f(unsigned short u) {
    unsigned int x = ((unsigned int)u) << 16;
    return __uint_as_float(x);
}
__device__ __forceinline__ unsigned short f2us(float f) {
    unsigned int x = __float_as_uint(f);
    unsigned int r = (x + 0x7fffu + ((x >> 16) & 1u)) >> 16;
    return (unsigned short)r;
}

// async global->LDS, 16 bytes per lane; LDS dest = wave-uniform base + lane*16
__device__ __forceinline__ void gl_lds16(const unsigned short* g, unsigned short* l) {
    __builtin_amdgcn_global_load_lds(
        (const __attribute__((address_space(1))) void*)g,
        (__attribute__((address_space(3))) void*)l, 16, 0, 0);
}

// =============== cast fp32 -> bf16, 8 elems/thread ===============
__global__ __launch_bounds__(256) void cast_bf16(const float* __restrict__ in,
                                                 unsigned short* __restrict__ out, int n8)
{
    int i = blockIdx.x * blockDim.x + threadIdx.x;
    if (i >= n8) return;
    const float4* p = (const float4*)(in + (size_t)i * 8);
    float4 a = p[0], b = p[1];
    __align__(16) unsigned short u[8];
    u[0] = f2us(a.x); u[1] = f2us(a.y); u[2] = f2us(a.z); u[3] = f2us(a.w);
    u[4] = f2us(b.x); u[5] = f2us(b.y); u[6] = f2us(b.z); u[7] = f2us(b.w);
    *(uint4*)(out + (size_t)i * 8) = *(const uint4*)u;
}

// =============== bf16 MFMA GEMM v2: C[M,N] = act(A[M,K] * B[N,K]^T) ===============
// 128x128 tile, BK=64, XOR-swizzled LDS staging (conflict-free frag reads),
// LDS-staged coalesced bf16 epilogue. grid(M/128, N/128): row-major-consecutive
// blocks => same-row col-tiles share an XCD (128 % 8 == 0).
template<int EPI, bool OUT_BF16>
__global__ __launch_bounds__(256) void gemm_bt_mfma(const unsigned short* __restrict__ A,
                                                    const unsigned short* __restrict__ B,
                                                    void* __restrict__ Cv,
                                                    int M, int N, int K)
{
    __shared__ unsigned short smem[17408];          // 34 KB: As(8192) + Bs(8192) | Cs(17408)
    unsigned short* As = smem;                      // [128][64] swizzled
    unsigned short* Bs = smem + 8192;

    const int tid  = threadIdx.x;
    const int lane = tid & 63;
    const int wv   = tid >> 6;
    const int m0   = blockIdx.x * 128;
    const int n0   = blockIdx.y * 128;
    const int wr   = (wv >> 1) * 64;
    const int wc   = (wv & 1) * 64;

    // ---- staging: 16 segs of 8 rows x 64 cols (1 KB); wave w -> segs 4j+w ----
    // lane l: row-in-seg = l>>3, k-block = (l&7) XOR-swizzled by row&7.
    const int lrow8 = lane >> 3;
    const int xcol  = ((lane & 7) ^ lrow8) << 3;    // swizzled k offset (elems)
    const unsigned short* Ag[4];
    const unsigned short* Bg[4];
    unsigned short* Al[4];
    unsigned short* Bl[4];
#pragma unroll
    for (int j = 0; j < 4; ++j) {
        const int seg = j * 4 + wv;
        const int row = seg * 8 + lrow8;
        Ag[j] = A + (size_t)(m0 + row) * K + xcol;
        Bg[j] = B + (size_t)(n0 + row) * K + xcol;
        Al[j] = As + seg * 512;
        Bl[j] = Bs + seg * 512;
    }

    f32x4 acc[4][4];
#pragma unroll
    for (int i = 0; i < 4; ++i)
#pragma unroll
        for (int j = 0; j < 4; ++j) acc[i][j] = (f32x4){0.f, 0.f, 0.f, 0.f};

    const int fr = lane & 15;          // fragment row within 16x16
    const int fq = lane >> 4;          // fragment k quad
    const int rx = fr & 7;             // read-side swizzle key

    for (int k0 = 0; k0 < K; k0 += 64) {
        __syncthreads();               // WAR: prior tile's ds_reads done
#pragma unroll
        for (int j = 0; j < 4; ++j) {
            gl_lds16(Ag[j] + k0, Al[j]);
            gl_lds16(Bg[j] + k0, Bl[j]);
        }
        __syncthreads();               // drains vmcnt before barrier

#pragma unroll
        for (int ks = 0; ks < 2; ++ks) {
            const int ka = (((ks << 2) + fq) ^ rx) << 3;   // swizzled k addr (elems)
            bf16x8 af[4], bfv[4];
#pragma unroll
            for (int ti = 0; ti < 4; ++ti)
                af[ti] = *(const bf16x8*)&As[(wr + ti * 16 + fr) * 64 + ka];
#pragma unroll
            for (int tj = 0; tj < 4; ++tj)
                bfv[tj] = *(const bf16x8*)&Bs[(wc + tj * 16 + fr) * 64 + ka];
#pragma unroll
            for (int ti = 0; ti < 4; ++ti)
#pragma unroll
                for (int tj = 0; tj < 4; ++tj)
                    acc[ti][tj] = __builtin_amdgcn_mfma_f32_16x16x32_bf16(
                        af[ti], bfv[tj], acc[ti][tj], 0, 0, 0);
        }
    }

    // C/D layout: col = lane&15, row = (lane>>4)*4 + reg
    const int crow = (lane >> 4) * 4;
    const int ccol = lane & 15;

    if (OUT_BF16) {
        __syncthreads();               // done reading As/Bs; reuse smem as C-tile
        unsigned short* Cs = smem;     // [128][136]
#pragma unroll
        for (int ti = 0; ti < 4; ++ti)
#pragma unroll
            for (int r = 0; r < 4; ++r)
#pragma unroll
                for (int tj = 0; tj < 4; ++tj) {
                    float z = acc[ti][tj][r];
                    if (EPI == EPI_SILU) {
                        z = z / (1.f + __expf(-z));
                    } else if (EPI == EPI_LOGSIG) {
                        float s = 1.f / (1.f + __expf(-z));
                        z = -log1pf(__expf(-s));
                    }
                    Cs[(wr + ti * 16 + crow + r) * 136 + wc + tj * 16 + ccol] = f2us(z);
                }
        __syncthreads();
        // coalesced store: thread t -> row t>>1, 64-col half t&1, 8x uint4
        const int row = tid >> 1, half = tid & 1;
        const unsigned short* src = &Cs[row * 136 + half * 64];
        unsigned short* dst = (unsigned short*)Cv + (size_t)(m0 + row) * N + n0 + half * 64;
#pragma unroll
        for (int i = 0; i < 8; ++i)
            *(uint4*)(dst + i * 8) = *(const uint4*)(src + i * 8);
    } else {
        float* C = (float*)Cv;
#pragma unroll
        for (int ti = 0; ti < 4; ++ti)
#pragma unroll
            for (int r = 0; r < 4; ++r) {
                const int row = m0 + wr + ti * 16 + crow + r;
#pragma unroll
                for (int tj = 0; tj < 4; ++tj) {
                    float z = acc[ti][tj][r];
                    if (EPI == EPI_SILU) {
                        z = z / (1.f + __expf(-z));
                    } else if (EPI == EPI_LOGSIG) {
                        float s = 1.f / (1.f + __expf(-z));
                        z = -log1pf(__expf(-s));
                    }
                    C[(size_t)row * N + n0 + wc + tj * 16 + ccol] = z;
                }
            }
    }
}

// =============== GLA pass A1: decays + scores + intra (per chunk,bh) ===============
__global__ __launch_bounds__(256) void gla_a1(unsigned short* __restrict__ qb,
                                              unsigned short* __restrict__ lfb,
                                              const unsigned short* __restrict__ vb,
                                              unsigned short* __restrict__ obf,
                                              float* __restrict__ dbuf)
{
    __shared__ unsigned short q_sh[64][136];
    __shared__ unsigned short kd_sh[64][136];
    __shared__ unsigned short vT[128][72];   // v^T [f][t]
    __shared__ unsigned short sc[64][72];    // scores [t][s]

    const int tid = threadIdx.x;
    const int bid = blockIdx.x;
    const int c = bid >> 6, bh = bid & 63;
    const int b = bh >> 4, h = bh & 15;
    const size_t tok0 = ((size_t)b * 4096 + (size_t)c * 64) * 2048 + (size_t)h * 128;

#pragma unroll
    for (int k = 0; k < 4; ++k) {
        int vi = tid + k * 256;
        int t = vi >> 4, e8 = (vi & 15) << 3;
        *(uint4*)&q_sh[t][e8]  = *(const uint4*)(qb  + tok0 + (size_t)t * 2048 + e8);
        *(uint4*)&kd_sh[t][e8] = *(const uint4*)(lfb + tok0 + (size_t)t * 2048 + e8);
    }
    if (tid < 128) {
        int t8 = tid >> 4, f8 = tid & 15;
        __align__(16) unsigned short a[8][8];
#pragma unroll
        for (int r = 0; r < 8; ++r)
            *(uint4*)a[r] = *(const uint4*)(vb + tok0 + (size_t)(t8 * 8 + r) * 2048 + f8 * 8);
#pragma unroll
        for (int j = 0; j < 8; ++j) {
            __align__(16) unsigned short w8[8];
#pragma unroll
            for (int r = 0; r < 8; ++r) w8[r] = a[r][j];
            *(uint4*)&vT[f8 * 8 + j][t8 * 8] = *(const uint4*)w8;
        }
    }
    __syncthreads();
    if (tid < 128) {
        const int e = tid;
        float a = 0.f;
        for (int t = 0; t < 64; ++t) {
            float lf = us2f(kd_sh[t][e]);
            a += lf;
            q_sh[t][e]  = f2us(us2f(q_sh[t][e]) * __expf(a));       // q_dec
            kd_sh[t][e] = f2us((1.f - __expf(lf)) * __expf(-a));    // k_dec
        }
        dbuf[(size_t)bid * 128 + e] = __expf(a);
    }
    __syncthreads();
#pragma unroll
    for (int k = 0; k < 4; ++k) {
        int vi = tid + k * 256;
        int t = vi >> 4, e8 = (vi & 15) << 3;
        *(uint4*)(qb  + tok0 + (size_t)t * 2048 + e8) = *(const uint4*)&q_sh[t][e8];
        *(uint4*)(lfb + tok0 + (size_t)t * 2048 + e8) = *(const uint4*)&kd_sh[t][e8];
    }

    const int lane = tid & 63, w = tid >> 6;
    const int fr = lane & 15, fq = lane >> 4;

    // scores = qdec @ kdec^T
    f32x4 sacc[4];
#pragma unroll
    for (int j = 0; j < 4; ++j) sacc[j] = (f32x4){0.f, 0.f, 0.f, 0.f};
#pragma unroll
    for (int ke = 0; ke < 4; ++ke) {
        bf16x8 af = *(const bf16x8*)&q_sh[16 * w + fr][ke * 32 + fq * 8];
#pragma unroll
        for (int tj = 0; tj < 4; ++tj) {
            bf16x8 bfv = *(const bf16x8*)&kd_sh[16 * tj + fr][ke * 32 + fq * 8];
            sacc[tj] = __builtin_amdgcn_mfma_f32_16x16x32_bf16(af, bfv, sacc[tj], 0, 0, 0);
        }
    }
#pragma unroll
    for (int tj = 0; tj < 4; ++tj)
#pragma unroll
        for (int r = 0; r < 4; ++r) {
            int trow = 16 * w + fq * 4 + r;
            int scol = 16 * tj + fr;
            sc[trow][scol] = f2us(scol <= trow ? sacc[tj][r] : 0.f);
        }
    __syncthreads();
    // intra = sc @ v
    f32x4 oacc[8];
#pragma unroll
    for (int j = 0; j < 8; ++j) oacc[j] = (f32x4){0.f, 0.f, 0.f, 0.f};
#pragma unroll
    for (int ks = 0; ks < 2; ++ks) {
        bf16x8 af = *(const bf16x8*)&sc[16 * w + fr][ks * 32 + fq * 8];
#pragma unroll
        for (int tf = 0; tf < 8; ++tf) {
            bf16x8 bfv = *(const bf16x8*)&vT[16 * tf + fr][ks * 32 + fq * 8];
            oacc[tf] = __builtin_amdgcn_mfma_f32_16x16x32_bf16(af, bfv, oacc[tf], 0, 0, 0);
        }
    }
#pragma unroll
    for (int tf = 0; tf < 8; ++tf) {
        __align__(8) unsigned short o4[4];
#pragma unroll
        for (int r = 0; r < 4; ++r) o4[r] = f2us(oacc[tf][r]);
        *(uint2*)(obf + (((size_t)bid * 4 + w) * 8 + tf) * 256 + lane * 4) = *(const uint2*)o4;
    }
}

// =============== GLA pass A2: U^T[f][e] = d[e] * sum_t kdec[t][e] v[t][f] ===============
__global__ __launch_bounds__(256) void gla_a2(const unsigned short* __restrict__ lfb, // kdec
                                              const unsigned short* __restrict__ vb,
                                              const float* __restrict__ dbuf,
                                              unsigned short* __restrict__ UT)
{
    __shared__ unsigned short vT[128][72];
    __shared__ unsigned short kdT[128][72];
    __shared__ float d_sh[128];

    const int tid = threadIdx.x;
    const int bid = blockIdx.x;
    const int c = bid >> 6, bh = bid & 63;
    const int b = bh >> 4, h = bh & 15;
    const size_t tok0 = ((size_t)b * 4096 + (size_t)c * 64) * 2048 + (size_t)h * 128;

    if (tid < 128) {
        int t8 = tid >> 4, f8 = tid & 15;
        __align__(16) unsigned short a[8][8];
#pragma unroll
        for (int r = 0; r < 8; ++r)
            *(uint4*)a[r] = *(const uint4*)(vb + tok0 + (size_t)(t8 * 8 + r) * 2048 + f8 * 8);
#pragma unroll
        for (int j = 0; j < 8; ++j) {
            __align__(16) unsigned short w8[8];
#pragma unroll
            for (int r = 0; r < 8; ++r) w8[r] = a[r][j];
            *(uint4*)&vT[f8 * 8 + j][t8 * 8] = *(const uint4*)w8;
        }
        d_sh[tid] = dbuf[(size_t)bid * 128 + tid];
    } else {
        int i = tid - 128;
        int t8 = i >> 4, e8b = i & 15;
        __align__(16) unsigned short a[8][8];
#pragma unroll
        for (int r = 0; r < 8; ++r)
            *(uint4*)a[r] = *(const uint4*)(lfb + tok0 + (size_t)(t8 * 8 + r) * 2048 + e8b * 8);
#pragma unroll
        for (int j = 0; j < 8; ++j) {
            __align__(16) unsigned short w8[8];
#pragma unroll
            for (int r = 0; r < 8; ++r) w8[r] = a[r][j];
            *(uint4*)&kdT[e8b * 8 + j][t8 * 8] = *(const uint4*)w8;
        }
    }
    __syncthreads();

    const int lane = tid & 63, w = tid >> 6;
    const int fr = lane & 15, fq = lane >> 4;

    f32x4 acc[2][8];
#pragma unroll
    for (int mi = 0; mi < 2; ++mi)
#pragma unroll
        for (int te = 0; te < 8; ++te) acc[mi][te] = (f32x4){0.f, 0.f, 0.f, 0.f};
#pragma unroll
    for (int kt = 0; kt < 2; ++kt) {
        bf16x8 af0 = *(const bf16x8*)&vT[16 * (2 * w + 0) + fr][kt * 32 + fq * 8];
        bf16x8 af1 = *(const bf16x8*)&vT[16 * (2 * w + 1) + fr][kt * 32 + fq * 8];
#pragma unroll
        for (int te = 0; te < 8; ++te) {
            bf16x8 bfv = *(const bf16x8*)&kdT[16 * te + fr][kt * 32 + fq * 8];
            acc[0][te] = __builtin_amdgcn_mfma_f32_16x16x32_bf16(af0, bfv, acc[0][te], 0, 0, 0);
            acc[1][te] = __builtin_amdgcn_mfma_f32_16x16x32_bf16(af1, bfv, acc[1][te], 0, 0, 0);
        }
    }
    unsigned short* up = UT + (size_t)bid * 16384;
#pragma unroll
    for (int mi = 0; mi < 2; ++mi)
#pragma unroll
        for (int te = 0; te < 8; ++te) {
            int e = 16 * te + fr;
            float dv = d_sh[e];
#pragma unroll
            for (int r = 0; r < 4; ++r) {
                int f = 32 * w + 16 * mi + fq * 4 + r;
                up[f * 128 + e] = f2us(acc[mi][te][r] * dv);
            }
        }
}

// =============== GLA pass B: in-place scan UT[c] -> S-before-chunk-c ===============
__global__ __launch_bounds__(256) void gla_scan(unsigned short* __restrict__ UT,
                                                const float* __restrict__ dbuf)
{
    const int tid = threadIdx.x;
    const int bh = blockIdx.x >> 3, fs = blockIdx.x & 7;
    const int f = fs * 16 + (tid >> 4);
    const int e8 = (tid & 15) << 3;
    float S[8];
#pragma unroll
    for (int j = 0; j < 8; ++j) S[j] = 0.f;
    for (int c = 0; c < 64; ++c) {
        const size_t cb = (size_t)(c * 64 + bh);
        const size_t loc = cb * 16384 + (size_t)f * 128 + e8;
        uint4 uu = *(const uint4*)(UT + loc);
        float4 d0 = *(const float4*)(dbuf + cb * 128 + e8);
        float4 d1 = *(const float4*)(dbuf + cb * 128 + e8 + 4);
        __align__(16) unsigned short us8[8];
        *(uint4*)us8 = uu;
        __align__(16) unsigned short so[8];
#pragma unroll
        for (int j = 0; j < 8; ++j) so[j] = f2us(S[j]);
        *(uint4*)(UT + loc) = *(const uint4*)so;
        float dd[8] = {d0.x, d0.y, d0.z, d0.w, d1.x, d1.y, d1.z, d1.w};
#pragma unroll
        for (int j = 0; j < 8; ++j) S[j] = fmaf(dd[j], S[j], us2f(us8[j]));
    }
}

// =============== GLA pass C: o = intra + qdec @ S^T; write o over qb ===============
__global__ __launch_bounds__(256) void gla_c(unsigned short* __restrict__ qb,
                                             const unsigned short* __restrict__ UT, // = S^T[f][e]
                                             const unsigned short* __restrict__ obf)
{
    __shared__ unsigned short q_sh[64][136];
    __shared__ unsigned short ST_sh[128][136];

    const int tid = threadIdx.x;
    const int bid = blockIdx.x;
    const int c = bid >> 6, bh = bid & 63;
    const int b = bh >> 4, h = bh & 15;
    const size_t tok0 = ((size_t)b * 4096 + (size_t)c * 64) * 2048 + (size_t)h * 128;

#pragma unroll
    for (int k = 0; k < 4; ++k) {
        int vi = tid + k * 256;
        int t = vi >> 4, e8 = (vi & 15) << 3;
        *(uint4*)&q_sh[t][e8] = *(const uint4*)(qb + tok0 + (size_t)t * 2048 + e8);
    }
    const unsigned short* stp = UT + (size_t)bid * 16384;
#pragma unroll
    for (int k = 0; k < 8; ++k) {
        int vi = tid + k * 256;
        int f = vi >> 4, e8 = (vi & 15) << 3;
        *(uint4*)&ST_sh[f][e8] = *(const uint4*)(stp + (size_t)f * 128 + e8);
    }
    const int lane = tid & 63, w = tid >> 6;
    const int fr = lane & 15, fq = lane >> 4;

    f32x4 acc[8];
#pragma unroll
    for (int tf = 0; tf < 8; ++tf) {
        uint2 iv = *(const uint2*)(obf + (((size_t)bid * 4 + w) * 8 + tf) * 256 + lane * 4);
        __align__(8) unsigned short s4[4];
        *(uint2*)s4 = iv;
        acc[tf] = (f32x4){us2f(s4[0]), us2f(s4[1]), us2f(s4[2]), us2f(s4[3])};
    }
    __syncthreads();
#pragma unroll
    for (int ke = 0; ke < 4; ++ke) {
        bf16x8 af = *(const bf16x8*)&q_sh[16 * w + fr][ke * 32 + fq * 8];
#pragma unroll
        for (int tf = 0; tf < 8; ++tf) {
            bf16x8 bfv = *(const bf16x8*)&ST_sh[16 * tf + fr][ke * 32 + fq * 8];
            acc[tf] = __builtin_amdgcn_mfma_f32_16x16x32_bf16(af, bfv, acc[tf], 0, 0, 0);
        }
    }
#pragma unroll
    for (int tf = 0; tf < 8; ++tf)
#pragma unroll
        for (int r = 0; r < 4; ++r) {
            int t = 16 * w + fq * 4 + r;
            qb[tok0 + (size_t)t * 2048 + 16 * tf + fr] = f2us(acc[tf][r]);
        }
}

// =============== RMSNorm (in-place, bf16) ===============
__global__ __launch_bounds__(256) void rmsnorm_kernel(unsigned short* __restrict__ o,
                                                      const float* __restrict__ w)
{
    __shared__ float red[4];
    const int row = blockIdx.x;
    const int tid = threadIdx.x;
    unsigned short* p = o + (size_t)row * 2048 + tid * 8;
    __align__(16) unsigned short u[8];
    *(uint4*)u = *(const uint4*)p;
    float f[8];
    float ss = 0.f;
#pragma unroll
    for (int j = 0; j < 8; ++j) { f[j] = us2f(u[j]); ss = fmaf(f[j], f[j], ss); }
#pragma unroll
    for (int off = 32; off > 0; off >>= 1) ss += __shfl_down(ss, off, 64);
    if ((tid & 63) == 0) red[tid >> 6] = ss;
    __syncthreads();
    float tot = red[0] + red[1] + red[2] + red[3];
    float scale = rsqrtf(tot * (1.f / 2048.f) + 1e-6f);
    const float* wp = w + tid * 8;
#pragma unroll
    for (int j = 0; j < 8; ++j) u[j] = f2us(f[j] * scale * wp[j]);
    *(uint4*)p = *(const uint4*)u;
}

extern "C" void kernel_launch(void* const* d_in, const int* in_sizes, int n_in,
                              void* d_out, int out_size, void* d_ws, size_t ws_size,
                              hipStream_t stream)
{
    const float* x  = (const float*)d_in[0];
    const float* Wq = (const float*)d_in[1];
    const float* Wk = (const float*)d_in[2];
    const float* Wv = (const float*)d_in[3];
    const float* Wo = (const float*)d_in[4];
    const float* nw = (const float*)d_in[5];
    float* out = (float*)d_out;

    const int M = 16384, N = 2048, K = 2048;
    const size_t S1 = (size_t)M * N;
    const size_t SW = (size_t)N * K;
    const size_t UTsz = (size_t)4096 * 16384;

    unsigned short* xb  = (unsigned short*)d_ws;
    unsigned short* Wqb = xb + S1;
    unsigned short* Wkb = Wqb + SW;
    unsigned short* Wvb = Wkb + SW;
    unsigned short* Wob = Wvb + SW;
    unsigned short* qb  = Wob + SW;   // q -> qdec -> o
    unsigned short* vbf = qb + S1;
    unsigned short* lfb = vbf + S1;   // log_f -> kdec
    unsigned short* obf = lfb + S1;   // intra frags
    unsigned short* UT  = obf + S1;   // U^T then S^T (in-place scan)
    float* dbuf = (float*)(UT + UTsz);

    cast_bf16<<<(int)(S1 / 8 / 256), 256, 0, stream>>>(x, xb, (int)(S1 / 8));
    cast_bf16<<<(int)(SW / 8 / 256), 256, 0, stream>>>(Wq, Wqb, (int)(SW / 8));
    cast_bf16<<<(int)(SW / 8 / 256), 256, 0, stream>>>(Wk, Wkb, (int)(SW / 8));
    cast_bf16<<<(int)(SW / 8 / 256), 256, 0, stream>>>(Wv, Wvb, (int)(SW / 8));
    cast_bf16<<<(int)(SW / 8 / 256), 256, 0, stream>>>(Wo, Wob, (int)(SW / 8));

    dim3 gg(M / 128, N / 128);  // row-major-consecutive => same-row tiles share XCD
    gemm_bt_mfma<EPI_SILU,  true><<<gg, 256, 0, stream>>>(xb, Wqb, qb,  M, N, K);
    gemm_bt_mfma<EPI_LOGSIG,true><<<gg, 256, 0, stream>>>(xb, Wkb, lfb, M, N, K);
    gemm_bt_mfma<EPI_NONE,  true><<<gg, 256, 0, stream>>>(xb, Wvb, vbf, M, N, K);

    gla_a1<<<4096, 256, 0, stream>>>(qb, lfb, vbf, obf, dbuf);
    gla_a2<<<4096, 256, 0, stream>>>(lfb, vbf, dbuf, UT);
    gla_scan<<<512, 256, 0, stream>>>(UT, dbuf);
    gla_c<<<4096, 256, 0, stream>>>(qb, UT, obf);

    rmsnorm_kernel<<<16384, 256, 0, stream>>>(qb, nw);
    gemm_bt_mfma<EPI_NONE, false><<<gg, 256, 0, stream>>>(qb, Wob, out, M, N, K);
}